// Round 9
// baseline (1687.499 us; speedup 1.0000x reference)
//
#include <hip/hip_runtime.h>
#include <hip/hip_bf16.h>

// Problem constants
#define TT 2048
#define KK 6
#define EE 32
#define DD 2048
#define FF 1408
#define SS 2
#define CC 384   // TT*KK/EE

typedef __bf16 bf16_t;
typedef __attribute__((ext_vector_type(8))) __bf16 bf16x8;
typedef __attribute__((ext_vector_type(4))) float f32x4;
typedef unsigned int u32;

#define AS1 __attribute__((address_space(1)))
#define AS3 __attribute__((address_space(3)))

__device__ __forceinline__ u32 f2bf(float f) {
    u32 u = __builtin_bit_cast(u32, f);
    return (u + 0x7fffu + ((u >> 16) & 1u)) >> 16;   // RNE, no NaN in data
}
__device__ __forceinline__ u32 pack2(float a, float b) {
    return f2bf(a) | (f2bf(b) << 16);
}
__device__ __forceinline__ float silu_mul(float g, float u) {
    return (g / (1.0f + __expf(-g))) * u;
}

// ---------------- dispatch: pair -> slot (balanced: exactly CC per expert) ----
__global__ void k_dispatch(const int* __restrict__ idx, int* __restrict__ counts,
                           int* __restrict__ tok, int* __restrict__ sop) {
    int p = blockIdx.x * 256 + threadIdx.x;
    if (p >= TT * KK) return;
    int e = idx[p];
    int pos = atomicAdd(&counts[e], 1);
    int slot = e * CC + pos;
    tok[slot] = p / KK;
    sop[p] = slot;
}

// ---------------- gather + fp32->bf16 convert --------------------------------
__global__ void k_gather(const float* __restrict__ x, const int* __restrict__ tok,
                         bf16_t* __restrict__ xall) {
    int row = blockIdx.x;
    int srow = (row < EE * CC) ? tok[row] : (row - EE * CC);
    const float* src = x + (size_t)srow * DD;
    bf16_t* dst = xall + (size_t)row * DD;
    int c0 = threadIdx.x * 8;
    float4 a = *(const float4*)(src + c0);
    float4 b = *(const float4*)(src + c0 + 4);
    uint4 o;
    o.x = pack2(a.x, a.y); o.y = pack2(a.z, a.w);
    o.z = pack2(b.x, b.y); o.w = pack2(b.z, b.w);
    *(uint4*)(dst + c0) = o;
}

#define BSTR 40

// =====================================================================
// GEMM block body: 256 threads (4 waves, 2m x 2n), tile 128x128, BK=32.
// Single-buffered, 2 barriers per K-step (R0 structure: high block-TLP,
// ~18 KB LDS, low VGPR -> ~5 blocks/CU of independent barrier groups).
// A via global_load_lds with source pre-swizzle (ds_read 2-way, free).
// B fp32 -> regs -> cvt bf16 -> LDS transposed [n][k] (BSTR=40, no conflict).
// FUSED: block covers 64 gate cols + 64 up cols; silu*up in epilogue.
// =====================================================================
template<bool FUSED>
__device__ __forceinline__ void gemm_body(
    const bf16_t* __restrict__ A,      // 128 rows x Kdim
    const float* __restrict__ bsrc,    // per-thread B source (col bn resolved)
    bf16_t* __restrict__ Cout,         // output tile base
    int Kdim, int Bstr, int Ostr)
{
    __shared__ __align__(16) bf16_t As[128 * 32];   // 8 KB
    __shared__ __align__(16) bf16_t Bs[128 * BSTR]; // 10 KB

    const int tid = threadIdx.x;
    const int lane = tid & 63, wid = tid >> 6;
    const int m_off = (wid >> 1) * 64, wn = wid & 1;
    const int l15 = lane & 15, lq = lane >> 4;
    const int arow = tid >> 2, ac = tid & 3;   // A-stage: 64 rows x 4 chunks
    const int bn = tid & 127, kh = tid >> 7;   // B-stage: col, k-half

    f32x4 acc[4][4] = {};
    const int ks = Kdim >> 5;

    for (int kt = 0; kt < ks; ++kt) {
        const int k0 = kt << 5;
        // ---- stage A: 128x32 via glds, linear dest, swizzled source ----
        {
            const int c = ac ^ (arow & 3);
            const bf16_t* g0 = A + (size_t)arow * Kdim + (k0 + c * 8);
            const bf16_t* g1 = A + (size_t)(arow + 64) * Kdim + (k0 + c * 8);
            AS3 u32* l0 = (AS3 u32*)(void*)(As + (size_t)(wid * 16) * 32);
            AS3 u32* l1 = (AS3 u32*)(void*)(As + (size_t)(64 + wid * 16) * 32);
            __builtin_amdgcn_global_load_lds((const AS1 u32*)(const void*)g0, l0, 16, 0, 0);
            __builtin_amdgcn_global_load_lds((const AS1 u32*)(const void*)g1, l1, 16, 0, 0);
        }
        // ---- stage B: 32x128 fp32 coalesced, cvt, transposed LDS write ----
        {
            const float* sp = bsrc + (size_t)(k0 + kh * 16) * Bstr;
            float v[16];
            #pragma unroll
            for (int t = 0; t < 16; ++t) v[t] = sp[(size_t)t * Bstr];
            u32 p[8];
            #pragma unroll
            for (int t = 0; t < 8; ++t) p[t] = pack2(v[2 * t], v[2 * t + 1]);
            uint4 w0, w1;
            w0.x = p[0]; w0.y = p[1]; w0.z = p[2]; w0.w = p[3];
            w1.x = p[4]; w1.y = p[5]; w1.z = p[6]; w1.w = p[7];
            *(uint4*)(Bs + (size_t)bn * BSTR + kh * 16) = w0;
            *(uint4*)(Bs + (size_t)bn * BSTR + kh * 16 + 8) = w1;
        }
        __syncthreads();
        // ---- compute ----
        {
            bf16x8 af[4], bfr[4];
            #pragma unroll
            for (int i = 0; i < 4; ++i) {
                const int row = m_off + i * 16 + l15;
                af[i] = *(const bf16x8*)(As + (size_t)row * 32
                           + (size_t)((lq ^ (row & 3)) * 8));
            }
            #pragma unroll
            for (int j = 0; j < 4; ++j) {
                const int n_ds = FUSED ? (wn * 32 + (j & 1) * 16 + (j >> 1) * 64)
                                       : (wn * 64 + j * 16);
                bfr[j] = *(const bf16x8*)(Bs + (size_t)(n_ds + l15) * BSTR + lq * 8);
            }
            #pragma unroll
            for (int i = 0; i < 4; ++i)
                #pragma unroll
                for (int j = 0; j < 4; ++j)
                    acc[i][j] = __builtin_amdgcn_mfma_f32_16x16x32_bf16(af[i], bfr[j], acc[i][j], 0, 0, 0);
        }
        __syncthreads();
    }

    // ---- epilogue: C/D layout col=lane&15, row=quad*4+reg ----
    if (FUSED) {
        #pragma unroll
        for (int i = 0; i < 4; ++i)
            #pragma unroll
            for (int j = 0; j < 2; ++j) {
                const int n = wn * 32 + j * 16 + l15;
                #pragma unroll
                for (int rr = 0; rr < 4; ++rr) {
                    const int mm = m_off + i * 16 + lq * 4 + rr;
                    Cout[(size_t)mm * Ostr + n] = (bf16_t)silu_mul(acc[i][j][rr], acc[i][j + 2][rr]);
                }
            }
    } else {
        #pragma unroll
        for (int i = 0; i < 4; ++i)
            #pragma unroll
            for (int j = 0; j < 4; ++j) {
                const int n = wn * 64 + j * 16 + l15;
                #pragma unroll
                for (int rr = 0; rr < 4; ++rr) {
                    const int mm = m_off + i * 16 + lq * 4 + rr;
                    Cout[(size_t)mm * Ostr + n] = (bf16_t)acc[i][j][rr];
                }
            }
    }
}

// ---- routed: expert pinned to XCD e%8; within XCD, m-sibling blocks of a
// (e, n-slab) are ADJACENT (m fastest) so the B slab is fetched once into L2.
template<bool FUSED>
__global__ __launch_bounds__(256) void k_gemm_r(
    const bf16_t* __restrict__ Aall, const float* __restrict__ Br,
    bf16_t* __restrict__ Out, int Kdim, int Bstr, int Ostr, int NB)
{
    const int lin = blockIdx.x;
    const int xcd = lin & 7, j = lin >> 3;
    const int per_e = NB * 3;
    const int e = (j / per_e) * 8 + xcd;
    const int r = j % per_e;
    const int n = r / 3, m = r % 3;

    const bf16_t* A = Aall + ((size_t)e * CC + (size_t)m * 128) * Kdim;
    const float* Bbase = Br + (size_t)e * Kdim * Bstr;
    const int bn = threadIdx.x & 127;

    const float* bsrc;
    bf16_t* Cout;
    if (FUSED) {
        bsrc = Bbase + ((bn & 64) ? FF : 0) + n * 64 + (bn & 63);
        Cout = Out + ((size_t)e * CC + (size_t)m * 128) * Ostr + n * 64;
    } else {
        bsrc = Bbase + n * 128 + bn;
        Cout = Out + ((size_t)e * CC + (size_t)m * 128) * Ostr + n * 128;
    }
    gemm_body<FUSED>(A, bsrc, Cout, Kdim, Bstr, Ostr);
}

// ---- shared: key=(s, n-slab) pinned to XCD key%8; m fastest within key.
template<bool FUSED>
__global__ __launch_bounds__(256) void k_gemm_s(
    const bf16_t* __restrict__ Ash, const float* __restrict__ Bsh,
    bf16_t* __restrict__ Out, int Kdim, int Bstr, int Ostr, int ash_stride,
    int nkeys, int NBs)
{
    const int lin = blockIdx.x;
    const int xcd = lin & 7, j = lin >> 3;
    const int kq = j >> 4, m = j & 15;
    const int key = xcd + 8 * kq;
    if (key >= nkeys) return;
    const int s = key / NBs, nb = key % NBs;

    const bf16_t* A = Ash + ((size_t)s * ash_stride + (size_t)m * 128) * Kdim;
    const float* Bp = Bsh + (size_t)s * Kdim * Bstr;
    const int bn = threadIdx.x & 127;

    const float* bsrc;
    bf16_t* Cout;
    if (FUSED) {
        bsrc = Bp + ((bn & 64) ? FF : 0) + nb * 64 + (bn & 63);
        Cout = Out + ((size_t)s * TT + (size_t)m * 128) * Ostr + nb * 64;
    } else {
        bsrc = Bp + nb * 128 + bn;
        Cout = Out + ((size_t)s * TT + (size_t)m * 128) * Ostr + nb * 128;
    }
    gemm_body<FUSED>(A, bsrc, Cout, Kdim, Bstr, Ostr);
}

// ---------------- combine: weighted scatter of routed + shared add ----------
__global__ void k_combine(const bf16_t* __restrict__ down, const int* __restrict__ sop,
                          const float* __restrict__ wts, float* __restrict__ y) {
    int t = blockIdx.x;
    int d0 = threadIdx.x * 8;
    float a[8] = {0, 0, 0, 0, 0, 0, 0, 0};
    #pragma unroll
    for (int k = 0; k < KK; ++k) {
        int slot = sop[t * KK + k];
        float w = wts[t * KK + k];
        bf16x8 v = *(const bf16x8*)(down + (size_t)slot * DD + d0);
        #pragma unroll
        for (int j = 0; j < 8; ++j) a[j] += w * (float)v[j];
    }
    #pragma unroll
    for (int s = 0; s < SS; ++s) {
        bf16x8 v = *(const bf16x8*)(down + ((size_t)EE * CC + (size_t)s * TT + t) * DD + d0);
        #pragma unroll
        for (int j = 0; j < 8; ++j) a[j] += (float)v[j];
    }
    float4 o0, o1;
    o0.x = a[0]; o0.y = a[1]; o0.z = a[2]; o0.w = a[3];
    o1.x = a[4]; o1.y = a[5]; o1.z = a[6]; o1.w = a[7];
    *(float4*)(y + (size_t)t * DD + d0) = o0;
    *(float4*)(y + (size_t)t * DD + d0 + 4) = o1;
}

extern "C" void kernel_launch(void* const* d_in, const int* in_sizes, int n_in,
                              void* d_out, int out_size, void* d_ws, size_t ws_size,
                              hipStream_t stream) {
    (void)in_sizes; (void)n_in; (void)out_size; (void)ws_size;
    const float* x      = (const float*)d_in[0];
    const float* wts    = (const float*)d_in[1];
    const float* w_gu   = (const float*)d_in[2];
    const float* w_dn   = (const float*)d_in[3];
    const float* w_gu_s = (const float*)d_in[4];
    const float* w_dn_s = (const float*)d_in[5];
    const int*   indices= (const int*)d_in[6];
    float* y = (float*)d_out;

    char* ws = (char*)d_ws;
    size_t off = 0;
    auto alloc = [&](size_t bytes) {
        void* p = ws + off;
        off = (off + bytes + 255) & ~(size_t)255;
        return p;
    };
    int*    counts = (int*)alloc((size_t)EE * 4);
    int*    tok    = (int*)alloc((size_t)EE * CC * 4);
    int*    sop    = (int*)alloc((size_t)TT * KK * 4);
    bf16_t* xall   = (bf16_t*)alloc((size_t)(EE * CC + TT) * DD * 2);
    bf16_t* actb   = (bf16_t*)alloc((size_t)(EE * CC + SS * TT) * FF * 2);
    bf16_t* dnout  = (bf16_t*)alloc((size_t)(EE * CC + SS * TT) * DD * 2);

    hipMemsetAsync(counts, 0, EE * 4, stream);
    k_dispatch<<<(TT * KK + 255) / 256, 256, 0, stream>>>(indices, counts, tok, sop);
    k_gather<<<EE * CC + TT, 256, 0, stream>>>(x, tok, xall);

    // ---- gate_up (K=DD, B stride 2*FF), silu fused -> actb ----
    // routed: 32 experts x 22 n-slabs x 3 m-sibs = 2112 blocks
    k_gemm_r<true><<<EE * 22 * 3, 256, 0, stream>>>(xall, w_gu, actb, DD, 2 * FF, FF, 22);
    // shared: nkeys = 2*22 = 44, ceil(44/8)=6 -> grid 8*6*16 = 768
    k_gemm_s<true><<<8 * 6 * 16, 256, 0, stream>>>(
        xall + (size_t)EE * CC * DD, w_gu_s, actb + (size_t)EE * CC * FF,
        DD, 2 * FF, FF, 0, 44, 22);

    // ---- down (K=FF, B stride DD) -> dnout ----
    // routed: 32 x 16 x 3 = 1536 blocks
    k_gemm_r<false><<<EE * 16 * 3, 256, 0, stream>>>(actb, w_dn, dnout, FF, DD, DD, 16);
    // shared: nkeys = 2*16 = 32, ceil(32/8)=4 -> grid 8*4*16 = 512
    k_gemm_s<false><<<8 * 4 * 16, 256, 0, stream>>>(
        actb + (size_t)EE * CC * FF, w_dn_s, dnout + (size_t)EE * CC * DD,
        FF, DD, DD, TT, 32, 16);

    k_combine<<<TT, 256, 0, stream>>>(dnout, sop, wts, y);
}